// Round 8
// baseline (222.522 us; speedup 1.0000x reference)
//
#include <hip/hip_runtime.h>
#include <stdint.h>
#include <stddef.h>

// Problem constants (B, F, D) = (1024, 16, 64); P = 120
constexpr int NB = 1024;
constexpr int NF = 16;
constexpr int ND = 64;
constexpr int NP = 120;
constexpr int KD = ND * ND;          // 4096 contraction length per pair
constexpr int OUT_STRIDE = NP * ND;  // 7680 floats per batch row

constexpr int BM = 256;              // batch rows per block
// 8 waves tile the 256x64 output as 4 m-groups (64 rows) x 2 n-groups (32 cols)

using floatx4 = __attribute__((ext_vector_type(4))) float;
using half8   = __attribute__((ext_vector_type(8))) _Float16;
using half2v  = __attribute__((ext_vector_type(2))) _Float16;
using fp16x2  = __attribute__((ext_vector_type(2))) __fp16;   // cvt_pkrtz return type
using uint4v  = __attribute__((ext_vector_type(4))) uint32_t;
using ushort4v = __attribute__((ext_vector_type(4))) uint16_t;

constexpr int BT_STRIDE = ND;              // u16 per W-tile row: 64, no pad (XOR-swizzled granules)
constexpr int BT_BUF    = ND * BT_STRIDE;  // 4096 u16 = 8 KiB per buffer
constexpr int NBUF      = 4;               // 4-deep ring: read-ahead target is already published

// pack 2 f32 -> 2 fp16 (v_cvt_pkrtz_f16_f32, 1 VALU op)
__device__ __forceinline__ half2v pkh2(float f0, float f1) {
    fp16x2 h = __builtin_amdgcn_cvt_pkrtz(f0, f1);
    return __builtin_bit_cast(half2v, h);
}
__device__ __forceinline__ uint32_t pk16(float f0, float f1) {
    fp16x2 h = __builtin_amdgcn_cvt_pkrtz(f0, f1);
    return __builtin_bit_cast(uint32_t, h);
}
__device__ __forceinline__ uint16_t f16bits(float f) {
    return __builtin_bit_cast(uint16_t, (_Float16)f);   // RNE scalar cvt
}

// Barrier that does NOT drain vmcnt: LDS ordering only (global W prefetch
// stays in flight across barriers; __syncthreads would force vmcnt(0)).
__device__ __forceinline__ void lds_barrier() {
    asm volatile("s_waitcnt lgkmcnt(0)" ::: "memory");
    __builtin_amdgcn_s_barrier();
    asm volatile("" ::: "memory");
}

struct XiU { uint32_t u[2]; };

__global__ __launch_bounds__(512, 4)
void outer_kernel(const float* __restrict__ x, const float* __restrict__ W,
                  const float* __restrict__ bias, float* __restrict__ out)
{
    // xi^T fp16, layout [a][wm][r][ms] (ms innermost -> one ds_read_b64 per wave-step)
    __shared__ uint16_t lds_xit[ND * BM];         // 32,768 B
    __shared__ uint16_t lds_bt[NBUF * BT_BUF];    // W a-tile 4-ring: 32,768 B (total 65,536 -> 2 blocks/CU)

    const int p  = blockIdx.x;        // pair 0..119
    const int b0 = blockIdx.y * BM;   // batch tile origin

    // triu_indices(16, k=1) order
    int icol = 0, rem = p;
    while (rem >= NF - 1 - icol) { rem -= NF - 1 - icol; ++icol; }
    const int jcol = icol + 1 + rem;

    const int t    = threadIdx.x;
    const int wave = t >> 6;
    const int lane = t & 63;
    const int r    = lane & 15;
    const int quad = lane >> 4;
    const int wm   = wave & 3;        // m-group: rows wm*64 .. wm*64+63
    const int wn   = wave >> 2;       // n-group: cols wn*32 .. wn*32+31

    // ---- stage xi transposed: lds_xit[a*256 + wm*64 + r*4 + ms] = fp16(x[b0+m][icol][a]) ----
    {
        const int mrow  = t >> 1;
        const int chalf = (t & 1) * 32;
        const int wms = mrow >> 6, mss = (mrow >> 4) & 3, rs = mrow & 15;
        const int dbase = wms * 64 + rs * 4 + mss;
        const float* src = x + (size_t)(b0 + mrow) * (NF * ND) + icol * ND + chalf;
        #pragma unroll
        for (int c = 0; c < 32; c += 4) {
            floatx4 v = *(const floatx4*)(src + c);
            lds_xit[(chalf + c + 0) * BM + dbase] = f16bits(v.x);
            lds_xit[(chalf + c + 1) * BM + dbase] = f16bits(v.y);
            lds_xit[(chalf + c + 2) * BM + dbase] = f16bits(v.z);
            lds_xit[(chalf + c + 3) * BM + dbase] = f16bits(v.w);
        }
    }

    // ---- loop-invariant xj as fp16 pairs, matching MFMA A-fragment layout ----
    half2v xjh[4][8];
    #pragma unroll
    for (int ms = 0; ms < 4; ++ms) {
        const float* srow = x + (size_t)(b0 + wm*64 + ms*16 + r) * (NF * ND)
                              + jcol * ND + quad * 8;
        #pragma unroll
        for (int ks = 0; ks < 2; ++ks) {
            floatx4 v0 = *(const floatx4*)(srow + ks * 32);
            floatx4 v1 = *(const floatx4*)(srow + ks * 32 + 4);
            xjh[ms][ks*4 + 0] = pkh2(v0.x, v0.y);
            xjh[ms][ks*4 + 1] = pkh2(v0.z, v0.w);
            xjh[ms][ks*4 + 2] = pkh2(v1.x, v1.y);
            xjh[ms][ks*4 + 3] = pkh2(v1.z, v1.w);
        }
    }

    // ---- W staging: thread covers (n_st, granule cg); XOR-swizzled slot cg ^ (n_st & 7) ----
    const int n_st = t >> 3;
    const int cg   = t & 7;
    const float* wsrc = W + ((size_t)p * ND + n_st) * KD + cg * 8;
    uint16_t* bdst0 = &lds_bt[n_st * BT_STRIDE + ((cg ^ (n_st & 7)) * 8)];

    // B-fragment read offsets (u16): first granule quad ^ (r&7); second is ^32
    const int xg0 = (quad ^ (r & 7)) * 8;

    auto packW = [&](int a2, const floatx4* wC) {   // pack W(a2) regs -> buf[a2 & 3]
        uint16_t* bd = bdst0 + (a2 & 3) * BT_BUF;
        uint4v q0 = (uint4v){ pk16(wC[0].x, wC[0].y), pk16(wC[0].z, wC[0].w),
                              pk16(wC[1].x, wC[1].y), pk16(wC[1].z, wC[1].w) };
        *(uint4v*)(bd) = q0;
    };
    auto loadW = [&](int a3, floatx4* wD) {         // issue global load of W(a3)
        const float* wp = wsrc + (size_t)a3 * ND;
        wD[0] = *(const floatx4*)(wp);
        wD[1] = *(const floatx4*)(wp + 4);
    };
    auto readfrags = [&](int a, half8 (&bfr)[2][2], XiU& xi) {  // ds_read frags for step a
        const uint16_t* rbuf = lds_bt + (a & 3) * BT_BUF;
        union { ushort4v s4; uint32_t u[2]; } xu;
        xu.s4 = *(const ushort4v*)&lds_xit[a * BM + wm * 64 + r * 4];
        xi.u[0] = xu.u[0]; xi.u[1] = xu.u[1];
        #pragma unroll
        for (int ns = 0; ns < 2; ++ns) {
            const int rowb = (wn*32 + ns*16 + r) * BT_STRIDE;
            bfr[ns][0] = *(const half8*)&rbuf[rowb + xg0];
            bfr[ns][1] = *(const half8*)&rbuf[rowb + (xg0 ^ 32)];
        }
    };

    floatx4 acc[4][2] = {};   // fp32 MFMA C-accumulators

    auto compute = [&](const half8 (&bfr)[2][2], const XiU& xi) {
        __builtin_amdgcn_s_setprio(1);
        #pragma unroll
        for (int ms = 0; ms < 4; ++ms) {
            const uint32_t xw = xi.u[ms >> 1];
            const uint32_t sel = (ms & 1) ? 0x03020302u : 0x01000100u;
            half2v xs = __builtin_bit_cast(half2v, __builtin_amdgcn_perm(xw, xw, sel));
            union { half8 h8; half2v h2[4]; } u0, u1;
            #pragma unroll
            for (int q2 = 0; q2 < 4; ++q2) {
                u0.h2[q2] = xs * xjh[ms][q2];       // v_pk_mul_f16
                u1.h2[q2] = xs * xjh[ms][4 + q2];
            }
            #pragma unroll
            for (int ns = 0; ns < 2; ++ns) {
                acc[ms][ns] = __builtin_amdgcn_mfma_f32_16x16x32_f16(
                    u0.h8, bfr[ns][0], acc[ms][ns], 0, 0, 0);
                acc[ms][ns] = __builtin_amdgcn_mfma_f32_16x16x32_f16(
                    u1.h8, bfr[ns][1], acc[ms][ns], 0, 0, 0);
            }
        }
        __builtin_amdgcn_s_setprio(0);
    };

    // ---- prologue: stage W(0),W(1) into buf0/buf1; W(2) prefetch in flight ----
    floatx4 wreg[2], wtmp[2];
    loadW(0, wreg);
    loadW(1, wtmp);
    packW(0, wreg);
    packW(1, wtmp);
    loadW(2, wreg);
    lds_barrier();            // publishes xit + buf0 + buf1; W(2) stays in flight

    half8 bfrA[2][2], bfrB[2][2];
    XiU xiA, xiB;
    readfrags(0, bfrA, xiA);  // frags for a=0 (compiler inserts the lgkm wait at first use)

    // ---- main loop: per step — pack W(a+2) (write-early), issue load W(a+3),
    //      ds_read frags(a+1) IN THE MFMA SHADOW, MFMA step a, lds-only barrier ----
    #pragma unroll 1
    for (int a = 0; a < ND; a += 2) {
        // even substep: consume A, read-ahead into B
        if (a + 2 < ND) packW(a + 2, wreg);
        if (a + 3 < ND) loadW(a + 3, wreg);
        if (a + 1 < ND) readfrags(a + 1, bfrB, xiB);
        compute(bfrA, xiA);
        lds_barrier();
        // odd substep: consume B, read-ahead into A
        if (a + 3 < ND) packW(a + 3, wreg);
        if (a + 4 < ND) loadW(a + 4, wreg);
        if (a + 2 < ND) readfrags(a + 2, bfrA, xiA);
        compute(bfrB, xiB);
        lds_barrier();
    }

    // ---- epilogue: bias + store. C/D: col = lane&15, row = quad*4 + reg ----
    #pragma unroll
    for (int ns = 0; ns < 2; ++ns) {
        const float bb = bias[p * ND + wn*32 + ns*16 + r];
        #pragma unroll
        for (int ms = 0; ms < 4; ++ms) {
            #pragma unroll
            for (int reg = 0; reg < 4; ++reg) {
                const int row = b0 + wm*64 + ms*16 + quad*4 + reg;
                out[(size_t)row * OUT_STRIDE + p * ND + wn*32 + ns*16 + r]
                    = acc[ms][ns][reg] + bb;
            }
        }
    }
}

extern "C" void kernel_launch(void* const* d_in, const int* in_sizes, int n_in,
                              void* d_out, int out_size, void* d_ws, size_t ws_size,
                              hipStream_t stream) {
    const float* x    = (const float*)d_in[0];  // (1024, 16, 64)
    const float* W    = (const float*)d_in[1];  // (120, 64, 4096)
    const float* bias = (const float*)d_in[2];  // (120, 64)
    float* out = (float*)d_out;                 // (1024, 120, 64)

    dim3 grid(NP, NB / BM);    // 480 blocks; same-p blocks land on one XCD (120 % 8 == 0)
    outer_kernel<<<grid, 512, 0, stream>>>(x, W, bias, out);
}